// Round 3
// baseline (1079.313 us; speedup 1.0000x reference)
//
#include <hip/hip_runtime.h>
#include <math.h>

#define NN_   6000
#define EE_   192000
#define CIN_  32
#define CHID_ 64
#define KK_   125   // 5^3 spline kernel cells
#define SS_   8     // 2^3 corners

// fp32 -> bf16 round-to-nearest-even
static __device__ __forceinline__ unsigned short f2bf(float f) {
    unsigned int u = __builtin_bit_cast(unsigned int, f);
    u += 0x7fff + ((u >> 16) & 1);
    return (unsigned short)(u >> 16);
}

// ---------------------------------------------------------------------------
// Bucketing: counting sort of edges by dst.
// ---------------------------------------------------------------------------
__global__ __launch_bounds__(256) void count_deg_kernel(
    const int* __restrict__ ei, int* __restrict__ deg)
{
    int e = blockIdx.x * 256 + threadIdx.x;
    if (e < EE_) atomicAdd(&deg[ei[EE_ + e]], 1);
}

// Single-block exclusive scan over NN_ entries -> offs[0..NN_], cursor copy.
__global__ __launch_bounds__(1024) void scan_kernel(
    const int* __restrict__ deg, int* __restrict__ offs, int* __restrict__ cursor)
{
    __shared__ int part[1024];
    const int tid = threadIdx.x;
    const int CH = (NN_ + 1023) / 1024;   // 6
    const int base = tid * CH;
    int loc[CH];
    int s = 0;
#pragma unroll
    for (int i = 0; i < CH; ++i) {
        int v = (base + i < NN_) ? deg[base + i] : 0;
        loc[i] = s; s += v;
    }
    part[tid] = s;
    __syncthreads();
    for (int off = 1; off < 1024; off <<= 1) {
        int v = (tid >= off) ? part[tid - off] : 0;
        __syncthreads();
        part[tid] += v;
        __syncthreads();
    }
    const int pre = (tid > 0) ? part[tid - 1] : 0;
#pragma unroll
    for (int i = 0; i < CH; ++i) {
        if (base + i < NN_) {
            offs[base + i]   = pre + loc[i];
            cursor[base + i] = pre + loc[i];
        }
    }
    if (tid == 1023) offs[NN_] = part[1023];
}

__global__ __launch_bounds__(256) void fill_perm_kernel(
    const int* __restrict__ ei, int* __restrict__ cursor, int* __restrict__ perm)
{
    int e = blockIdx.x * 256 + threadIdx.x;
    if (e < EE_) {
        int p = atomicAdd(&cursor[ei[EE_ + e]], 1);
        perm[p] = e;
    }
}

// ---------------------------------------------------------------------------
// Per-node T build: block = dst node, T_node in LDS (fp32, LDS atomics only),
// written once to global as bf16. No global atomics, no global memset.
// C=64: wave handles one edge, lane = channel, loop s=0..7.
// C=32: wave handles one edge, lane = (s parity, channel), loop s-pairs.
// ---------------------------------------------------------------------------
template<int C>
__global__ __launch_bounds__(256) void build_T_kernel(
    const int* __restrict__ ei, const float* __restrict__ attr,
    const float* __restrict__ feat, const int* __restrict__ offs,
    const int* __restrict__ perm, unsigned short* __restrict__ Tb)
{
    __shared__ float Tl[KK_ * C];
    const int node = blockIdx.x;
    const int tid  = threadIdx.x;
    const int wave = tid >> 6;
    const int lane = tid & 63;

    for (int i = tid; i < KK_ * C; i += 256) Tl[i] = 0.f;
    __syncthreads();

    const int j0 = offs[node], j1 = offs[node + 1];
    const int c    = lane & (C - 1);
    const int soff = (C == 32) ? (lane >> 5) : 0;

    for (int j = j0 + wave; j < j1; j += 4) {
        const int e   = perm[j];
        const int src = ei[e];
        float f[3]; int i0[3];
#pragma unroll
        for (int d = 0; d < 3; ++d) {
            float u  = attr[e * 3 + d] * 4.0f;
            float fl = floorf(u);
            fl = fminf(fmaxf(fl, 0.0f), 3.0f);
            i0[d] = (int)fl;
            f[d]  = u - fl;
        }
        const float xv = feat[(size_t)src * C + c];
        if constexpr (C == 64) {
#pragma unroll
            for (int s = 0; s < 8; ++s) {
                const int b0 = s & 1, b1 = (s >> 1) & 1, b2 = (s >> 2) & 1;
                const int idx = (i0[0] + b0) * 25 + (i0[1] + b1) * 5 + (i0[2] + b2);
                const float basis = (b0 ? f[0] : 1.0f - f[0]) *
                                    (b1 ? f[1] : 1.0f - f[1]) *
                                    (b2 ? f[2] : 1.0f - f[2]);
                atomicAdd(&Tl[idx * C + c], basis * xv);
            }
        } else {
#pragma unroll
            for (int sp = 0; sp < 8; sp += 2) {
                const int s = sp + soff;
                const int b0 = s & 1, b1 = (s >> 1) & 1, b2 = (s >> 2) & 1;
                const int idx = (i0[0] + b0) * 25 + (i0[1] + b1) * 5 + (i0[2] + b2);
                const float basis = (b0 ? f[0] : 1.0f - f[0]) *
                                    (b1 ? f[1] : 1.0f - f[1]) *
                                    (b2 ? f[2] : 1.0f - f[2]);
                atomicAdd(&Tl[idx * C + c], basis * xv);
            }
        }
    }
    __syncthreads();

    // coalesced bf16 writeout, 2 channels per uint
    unsigned int* To = (unsigned int*)(Tb + (size_t)node * (KK_ * C));
    for (int i = tid; i < (KK_ * C) / 2; i += 256) {
        unsigned int lo = f2bf(Tl[2 * i]);
        unsigned int hi = f2bf(Tl[2 * i + 1]);
        To[i] = lo | (hi << 16);
    }
}

// ---------------------------------------------------------------------------
// Pack weights into transposed bf16 B matrices: Bt[n][k], n = conv*64 + o,
// k = kcell*Cin + c.
// ---------------------------------------------------------------------------
__global__ void pack_x_kernel(const float* __restrict__ Wa,
                              const float* __restrict__ Wb,
                              const float* __restrict__ Wc,
                              unsigned short* __restrict__ B1t)
{
    int gid = blockIdx.x * 256 + threadIdx.x;
    if (gid >= 192 * (KK_ * CIN_)) return;
    int n  = gid / (KK_ * CIN_);
    int kk = gid % (KK_ * CIN_);
    int conv = n >> 6, o = n & 63;
    const float* W = (conv == 0) ? Wa : ((conv == 1) ? Wb : Wc);
    B1t[gid] = f2bf(W[(size_t)kk * 64 + o]);
}

__global__ void pack_h_kernel(const float* __restrict__ Wa,
                              const float* __restrict__ Wb,
                              unsigned short* __restrict__ B2t)
{
    int gid = blockIdx.x * 256 + threadIdx.x;
    if (gid >= 128 * (KK_ * CHID_)) return;
    int n  = gid / (KK_ * CHID_);
    int kk = gid % (KK_ * CHID_);
    int conv = n >> 6, o = n & 63;
    const float* W = (conv == 0) ? Wa : Wb;
    B2t[gid] = f2bf(W[(size_t)kk * 64 + o]);
}

// ---------------------------------------------------------------------------
// MFMA bf16 GEMM with split-K: C[M,NT] += A[M,Kd] x Bt[NT,Kd]^T.
// A and Bt bf16. 64-row tile x full NT, 4 waves, mfma_f32_16x16x32_bf16,
// fp32 atomicAdd into C (C is L2-resident, 3-4.6 MB).
// ---------------------------------------------------------------------------
template<int NT, int STEPS_PER_CHUNK>
__global__ __launch_bounds__(256) void mfma_gemm(
    const unsigned short* __restrict__ A, const unsigned short* __restrict__ Bt,
    float* __restrict__ C, int M, int Kd)
{
    constexpr int NFRAG = NT / 16;
    __shared__ unsigned short As[64][40];
    __shared__ unsigned short Bs[NT][40];

    using bf16x8 = __attribute__((ext_vector_type(8))) short;
    using f32x4  = __attribute__((ext_vector_type(4))) float;

    const int tid  = threadIdx.x;
    const int wave = tid >> 6;
    const int lane = tid & 63;
    const int quad = lane >> 4;
    const int l16  = lane & 15;
    const int m0   = blockIdx.x * 64;

    const int steps_total = Kd >> 5;
    const int s0 = blockIdx.y * STEPS_PER_CHUNK;
    const int s1 = min(steps_total, s0 + STEPS_PER_CHUNK);

    f32x4 acc[NFRAG];
#pragma unroll
    for (int f = 0; f < NFRAG; ++f) acc[f] = (f32x4){0.f, 0.f, 0.f, 0.f};

    const int  arow   = tid >> 2;
    const int  acol   = (tid & 3) * 8;
    const bool avalid = (m0 + arow) < M;
    const unsigned short* Aptr = A + (size_t)(avalid ? (m0 + arow) : 0) * Kd + acol;

    for (int s = s0; s < s1; ++s) {
        const int k0 = s << 5;
        uint4 a4 = make_uint4(0u, 0u, 0u, 0u);
        if (avalid) a4 = *(const uint4*)(Aptr + k0);
        *(uint4*)&As[arow][acol] = a4;

#pragma unroll
        for (int cc = tid; cc < NT * 4; cc += 256) {
            int n = cc >> 2, kc = (cc & 3) * 8;
            *(uint4*)&Bs[n][kc] = *(const uint4*)(Bt + (size_t)n * Kd + k0 + kc);
        }
        __syncthreads();

        bf16x8 af = *(bf16x8*)&As[wave * 16 + l16][quad * 8];
#pragma unroll
        for (int f = 0; f < NFRAG; ++f) {
            bf16x8 bfv = *(bf16x8*)&Bs[f * 16 + l16][quad * 8];
            acc[f] = __builtin_amdgcn_mfma_f32_16x16x32_bf16(af, bfv, acc[f], 0, 0, 0);
        }
        __syncthreads();
    }

#pragma unroll
    for (int f = 0; f < NFRAG; ++f) {
#pragma unroll
        for (int r = 0; r < 4; ++r) {
            int m = m0 + wave * 16 + quad * 4 + r;
            if (m < M) atomicAdd(&C[(size_t)m * NT + f * 16 + l16], acc[f][r]);
        }
    }
}

// ---------------------------------------------------------------------------
// Epilogue: mean-agg + root GEMV + bias + GRU gates, fused.
// ---------------------------------------------------------------------------
__global__ __launch_bounds__(256) void epilogue_kernel(
    const float* __restrict__ C1, const float* __restrict__ C2,
    const int* __restrict__ deg,
    const float* __restrict__ x, const float* __restrict__ hidden,
    const float* __restrict__ root_xr, const float* __restrict__ root_hr,
    const float* __restrict__ root_xz, const float* __restrict__ root_hz,
    const float* __restrict__ root_xn,
    const float* __restrict__ b_xr, const float* __restrict__ b_hr,
    const float* __restrict__ b_xz, const float* __restrict__ b_hz,
    const float* __restrict__ b_xn,
    float* __restrict__ out)
{
    const int node = blockIdx.x * 4 + (threadIdx.x >> 6);
    if (node >= NN_) return;
    const int o = threadIdx.x & 63;

    const float dinv = 1.0f / fmaxf((float)deg[node], 1.0f);
    const float axr = C1[(size_t)node * 192 + o]        * dinv;
    const float axz = C1[(size_t)node * 192 + 64 + o]   * dinv;
    const float axn = C1[(size_t)node * 192 + 128 + o]  * dinv;
    const float ahr = C2[(size_t)node * 128 + o]        * dinv;
    const float ahz = C2[(size_t)node * 128 + 64 + o]   * dinv;

    const float* xr_ = x + (size_t)node * CIN_;
    const float* hr_ = hidden + (size_t)node * CHID_;
    float sxr = 0.f, sxz = 0.f, sxn = 0.f;
#pragma unroll
    for (int c = 0; c < CIN_; ++c) {
        float xv = xr_[c];
        sxr += xv * root_xr[c * 64 + o];
        sxz += xv * root_xz[c * 64 + o];
        sxn += xv * root_xn[c * 64 + o];
    }
    float shr = 0.f, shz = 0.f;
#pragma unroll
    for (int c = 0; c < CHID_; ++c) {
        float hv = hr_[c];
        shr += hv * root_hr[c * 64 + o];
        shz += hv * root_hz[c * 64 + o];
    }

    const float conv_xr = axr + sxr + b_xr[o];
    const float conv_xz = axz + sxz + b_xz[o];
    const float conv_xn = axn + sxn + b_xn[o];
    const float hr_out  = ahr + shr + b_hr[o];
    const float conv_hz = ahz + shz + b_hz[o];

    const float r  = 1.0f / (1.0f + expf(-(conv_xr + hr_out)));
    const float z  = 1.0f / (1.0f + expf(-(conv_xz + conv_hz)));
    const float nn = tanhf(conv_xn + r * hr_out);
    out[(size_t)node * 64 + o] = (1.0f - z) * nn + z * hr_[o];
}

// ---------------------------------------------------------------------------
extern "C" void kernel_launch(void* const* d_in, const int* in_sizes, int n_in,
                              void* d_out, int out_size, void* d_ws, size_t ws_size,
                              hipStream_t stream)
{
    const float* x       = (const float*)d_in[0];
    const float* hidden  = (const float*)d_in[1];
    const int*   ei      = (const int*)  d_in[2];
    const float* attr    = (const float*)d_in[3];
    const float* W_xr    = (const float*)d_in[4];
    const float* root_xr = (const float*)d_in[5];
    const float* b_xr    = (const float*)d_in[6];
    const float* W_hr    = (const float*)d_in[7];
    const float* root_hr = (const float*)d_in[8];
    const float* b_hr    = (const float*)d_in[9];
    const float* W_xz    = (const float*)d_in[10];
    const float* root_xz = (const float*)d_in[11];
    const float* b_xz    = (const float*)d_in[12];
    const float* W_hz    = (const float*)d_in[13];
    const float* root_hz = (const float*)d_in[14];
    const float* b_hz    = (const float*)d_in[15];
    const float* W_hn_dead = (const float*)d_in[16]; (void)W_hn_dead;
    const float* W_xn    = (const float*)d_in[16];
    const float* root_xn = (const float*)d_in[17];
    const float* b_xn    = (const float*)d_in[18];
    // d_in[19..21] (W_hn/root_hn/b_hn) are dead: reference reuses hr_out.
    float* out = (float*)d_out;

    // Workspace layout (~108 MB).
    char* w = (char*)d_ws;
    unsigned short* Tb  = (unsigned short*)w; w += (size_t)NN_ * KK_ * CHID_ * 2;  // 96 MB (h size; x uses half)
    unsigned short* B1t = (unsigned short*)w; w += (size_t)192 * KK_ * CIN_  * 2;
    unsigned short* B2t = (unsigned short*)w; w += (size_t)128 * KK_ * CHID_ * 2;
    float* C1   = (float*)w; w += (size_t)NN_ * 192 * 4;
    float* C2   = (float*)w; w += (size_t)NN_ * 128 * 4;
    int* deg    = (int*)w;   w += (size_t)NN_ * 4;
    int* offs   = (int*)w;   w += (size_t)(NN_ + 4) * 4;
    int* cursor = (int*)w;   w += (size_t)NN_ * 4;
    int* perm   = (int*)w;   w += (size_t)EE_ * 4;

    const int MT = (NN_ + 63) / 64;   // 94 m-tiles

    // ---- bucket edges by dst (shared by both passes) ----
    hipMemsetAsync(deg, 0, (size_t)NN_ * 4, stream);
    hipMemsetAsync(C1, 0, (size_t)NN_ * 192 * 4, stream);
    hipMemsetAsync(C2, 0, (size_t)NN_ * 128 * 4, stream);
    count_deg_kernel<<<(EE_ + 255) / 256, 256, 0, stream>>>(ei, deg);
    scan_kernel<<<1, 1024, 0, stream>>>(deg, offs, cursor);
    fill_perm_kernel<<<(EE_ + 255) / 256, 256, 0, stream>>>(ei, cursor, perm);

    // ---- weight packs (independent of T) ----
    pack_x_kernel<<<(192 * KK_ * CIN_ + 255) / 256, 256, 0, stream>>>(W_xr, W_xz, W_xn, B1t);
    pack_h_kernel<<<(128 * KK_ * CHID_ + 255) / 256, 256, 0, stream>>>(W_hr, W_hz, B2t);

    // ---- x family: T_x (bf16) -> C1 = T_x @ [W_xr | W_xz | W_xn] ----
    build_T_kernel<CIN_><<<NN_, 256, 0, stream>>>(ei, attr, x, offs, perm, Tb);
    mfma_gemm<192, 16><<<dim3(MT, 8), 256, 0, stream>>>(Tb, B1t, C1, NN_, KK_ * CIN_);

    // ---- h family: T_h (bf16) -> C2 = T_h @ [W_hr | W_hz] ----
    build_T_kernel<CHID_><<<NN_, 256, 0, stream>>>(ei, attr, hidden, offs, perm, Tb);
    mfma_gemm<128, 16><<<dim3(MT, 16), 256, 0, stream>>>(Tb, B2t, C2, NN_, KK_ * CHID_);

    // ---- fused GRU epilogue ----
    epilogue_kernel<<<(NN_ + 3) / 4, 256, 0, stream>>>(
        C1, C2, deg, x, hidden,
        root_xr, root_hr, root_xz, root_hz, root_xn,
        b_xr, b_hr, b_xz, b_hz, b_xn, out);
}